// Round 18
// baseline (97.269 us; speedup 1.0000x reference)
//
#include <hip/hip_runtime.h>
#include <hip/hip_bf16.h>

// 3D shifted-window attention, fully fused. R18 = R11 (best verified base:
// 101.8us profiled, VGPR 148) + cross-phase load prefetch:
//  (1) window A's xa issued BEFORE the weight stage, converted before the
//      barrier (stalls hide under staging + barrier wait);
//  (2) window B's xa issued + converted (2-sc pipelined, peak ~240 VGPR,
//      inside R15's proven 220+ no-spill envelope) between A's P2 and P3 --
//      B's P1 then starts with zero load stalls (hidden under A's P3+P4).
// R17 post-mortem: fast-pack + paired-QK reverted (compiler already emits
// v_cvt_pk_bf16_f32; pairing lengthened dep chains, dur 102->108).
// ONE WAVE = TWO WINDOWS, grid 512 x 256 threads; LDS = full weight pack
// (76.8 KB, SW=100 conflict-free); exp2 softmax (scale*log2e folded into W_q),
// tree-sum, setprio; Q/K/V in registers (swapped-proj D-frag == K=16 A-frag).
// Output window (p,q,r): QK from window (q,r,p), V from (p,q,r),
// x_mask iff q==15, y_mask iff r==15 (z_mask never applied - faithful to ref).
// Roll(-2) folded into loads, roll(+2) folded into stores.

using bf4   = __attribute__((ext_vector_type(4))) short;   // 4 x bf16 (2 VGPR)
using bf8   = __attribute__((ext_vector_type(8))) short;   // 8 x bf16 (4 VGPR)
using f32x4 = __attribute__((ext_vector_type(4))) float;

#define SW      100                  // weight row stride (shorts); conflict-free (R10)
#define WQ_ROWS 288
#define W_ROWS  384                  // 288 qkv + 96 out
#define W_SHORTS (W_ROWS * SW)       // 38400 shorts = 76800 B

__device__ __forceinline__ short f2b(float f) {
  __hip_bfloat16 h = __float2bfloat16(f);
  return *reinterpret_cast<short*>(&h);
}
__device__ __forceinline__ bf4 pk4(const f32x4& a) {
  bf4 s; s[0] = f2b(a[0]); s[1] = f2b(a[1]); s[2] = f2b(a[2]); s[3] = f2b(a[3]);
  return s;
}
__device__ __forceinline__ bf4 pk4s(const f32x4& a, float sc) {
  bf4 s; s[0] = f2b(a[0] * sc); s[1] = f2b(a[1] * sc);
  s[2] = f2b(a[2] * sc); s[3] = f2b(a[3] * sc);
  return s;
}
__device__ __forceinline__ bf8 cvt8(const float4& a, const float4& b) {
  bf8 o;
  o[0] = f2b(a.x); o[1] = f2b(a.y); o[2] = f2b(a.z); o[3] = f2b(a.w);
  o[4] = f2b(b.x); o[5] = f2b(b.y); o[6] = f2b(b.z); o[7] = f2b(b.w);
  return o;
}

#define mfma32 __builtin_amdgcn_mfma_f32_16x16x32_bf16

#if __has_builtin(__builtin_amdgcn_mfma_f32_16x16x16bf16_1k)
__device__ __forceinline__ f32x4 mfma16(bf4 a, bf4 b, f32x4 c) {
  return __builtin_amdgcn_mfma_f32_16x16x16bf16_1k(a, b, c, 0, 0, 0);
}
#elif __has_builtin(__builtin_amdgcn_mfma_f32_16x16x16_bf16)
__device__ __forceinline__ f32x4 mfma16(bf4 a, bf4 b, f32x4 c) {
  return __builtin_amdgcn_mfma_f32_16x16x16_bf16(a, b, c, 0, 0, 0);
}
#else
__device__ __forceinline__ f32x4 mfma16(bf4 a, bf4 b, f32x4 c) {
  asm("v_mfma_f32_16x16x16_bf16 %0, %1, %2, %0" : "+v"(c) : "v"(a), "v"(b));
  return c;
}
#endif

#if __has_builtin(__builtin_amdgcn_exp2f)
__device__ __forceinline__ float exp2n(float x) { return __builtin_amdgcn_exp2f(x); }
#else
__device__ __forceinline__ float exp2n(float x) {
  float r; asm("v_exp_f32 %0, %1" : "=v"(r) : "v"(x)); return r;
}
#endif

// d_ws weight pack: rows 0..95 = W_q * (scale*log2e), 96..287 = W_k/W_v,
// 288..383 = W_out; each row padded 96 -> 100 shorts (pad zeroed).
__global__ void prep_weights(const float* __restrict__ wq, const float* __restrict__ wo,
                             short* __restrict__ wpk) {
  int i = blockIdx.x * 256 + threadIdx.x;
  if (i >= W_SHORTS) return;
  int row = i / SW, c = i - row * SW;
  const float QS = 0.17677669529663687f * 1.4426950408889634f;  // scale*log2e
  float v = 0.f;
  if (c < 96) {
    if (row < 96)           v = wq[row * 96 + c] * QS;
    else if (row < WQ_ROWS) v = wq[row * 96 + c];
    else                    v = wo[(row - WQ_ROWS) * 96 + c];
  }
  wpk[i] = f2b(v);
}

// ---- per-window helpers (all __forceinline__, pure register plumbing) ------

// issue the 6 float4 xa loads for one site-chunk of window-source (wx,wy,wz)
__device__ __forceinline__ void issue_xa_sc(const float* __restrict__ x,
    int wx, int wy, int wz, int sc, int sy, int sz, int ch0, float4 fa[6]) {
  const int gx = (wx * 4 + sc + 2) & 63, gy = (wy * 4 + sy + 2) & 63, gz = (wz * 4 + sz + 2) & 63;
  const size_t b = (size_t)((gx * 64 + gy) * 64 + gz) * 96;
  #pragma unroll
  for (int f = 0; f < 3; ++f) {
    fa[f]     = *reinterpret_cast<const float4*>(&x[b + f * 32 + ch0]);
    fa[3 + f] = *reinterpret_cast<const float4*>(&x[b + f * 32 + ch0 + 4]);
  }
}
__device__ __forceinline__ void cvt_sc(const float4 fa[6], bf8 x1[3]) {
  x1[0] = cvt8(fa[0], fa[3]); x1[1] = cvt8(fa[1], fa[4]); x1[2] = cvt8(fa[2], fa[5]);
}

// P1: Q,K swapped proj from pre-converted x1 (W from LDS)
__device__ __forceinline__ void do_p1(const short* __restrict__ ls_w,
    const bf8 x1[4][3], int lr, int ch0, bf4 qn[4][6], bf4 kn[4][6]) {
  #pragma unroll
  for (int sc = 0; sc < 4; ++sc) {
    #pragma unroll
    for (int n = 0; n < 12; ++n) {
      f32x4 acc = {0.f, 0.f, 0.f, 0.f};
      const short* wrow = &ls_w[(n * 16 + lr) * SW + ch0];
      acc = mfma32(*reinterpret_cast<const bf8*>(wrow +  0), x1[sc][0], acc, 0, 0, 0);
      acc = mfma32(*reinterpret_cast<const bf8*>(wrow + 32), x1[sc][1], acc, 0, 0, 0);
      acc = mfma32(*reinterpret_cast<const bf8*>(wrow + 64), x1[sc][2], acc, 0, 0, 0);
      if (n < 6) qn[sc][n] = pk4(acc);
      else       kn[sc][n - 6] = pk4(acc);
    }
  }
}

// P2: V normal proj; loads xb itself per sc (R11 natural flow)
__device__ __forceinline__ void do_p2(const float* __restrict__ x,
    const short* __restrict__ ls_w, int p, int q, int r,
    int sy, int sz, int ch0, int lr, bf4 vn[4][6]) {
  #pragma unroll
  for (int sc = 0; sc < 4; ++sc) {
    float4 fb[6];
    issue_xa_sc(x, p, q, r, sc, sy, sz, ch0, fb);
    bf8 x2[3];
    cvt_sc(fb, x2);
    #pragma unroll
    for (int n = 0; n < 6; ++n) {
      f32x4 acc = {0.f, 0.f, 0.f, 0.f};
      const short* wrow = &ls_w[(192 + n * 16 + lr) * SW + ch0];
      acc = mfma32(x2[0], *reinterpret_cast<const bf8*>(wrow +  0), acc, 0, 0, 0);
      acc = mfma32(x2[1], *reinterpret_cast<const bf8*>(wrow + 32), acc, 0, 0, 0);
      acc = mfma32(x2[2], *reinterpret_cast<const bf8*>(wrow + 64), acc, 0, 0, 0);
      vn[sc][n] = pk4(acc);
    }
  }
}

// P3+P4 fused per q-chunk (identical math to R11)
__device__ __forceinline__ void do_p34(const short* __restrict__ ls_wo,
    const float* __restrict__ bo, float* __restrict__ out,
    int p, int q, int r, int sy, int sz, int ch0, int lr, int kg,
    const bf4 qn[4][6], const bf4 kn[4][6], const bf4 vn[4][6]) {
  const bool mx = (q == 15), my = (r == 15);
  const bool killy = my && ((lr >= 8) != (kg >= 2));

  #pragma unroll
  for (int qc = 0; qc < 4; ++qc) {
    f32x4 osw[6];
    #pragma unroll
    for (int c = 0; c < 6; ++c) osw[c] = (f32x4){0.f, 0.f, 0.f, 0.f};

    #pragma unroll
    for (int h = 0; h < 3; ++h) {
      f32x4 sv[4];   // S[i = qc*16+lr][j = nj*16 + kg*4 + reg], pre-scaled by log2e
      __builtin_amdgcn_s_setprio(1);
      #pragma unroll
      for (int nj = 0; nj < 4; ++nj) {
        f32x4 z = {0.f, 0.f, 0.f, 0.f};
        z = mfma16(kn[nj][2 * h + 0], qn[qc][2 * h + 0], z);
        sv[nj] = mfma16(kn[nj][2 * h + 1], qn[qc][2 * h + 1], z);
      }
      __builtin_amdgcn_s_setprio(0);
      float ps[4];
      #pragma unroll
      for (int nj = 0; nj < 4; ++nj) {
        const bool kill = killy || (mx && ((qc >= 2) != (nj >= 2)));
        #pragma unroll
        for (int t = 0; t < 4; ++t)
          sv[nj][t] = kill ? 0.f : exp2n(sv[nj][t]);
        ps[nj] = (sv[nj][0] + sv[nj][1]) + (sv[nj][2] + sv[nj][3]);
      }
      float sum = (ps[0] + ps[1]) + (ps[2] + ps[3]);
      sum += __shfl_xor(sum, 16);
      sum += __shfl_xor(sum, 32);
      const float inv = 1.f / sum;
      bf4 pb[4];
      #pragma unroll
      for (int t = 0; t < 4; ++t) pb[t] = pk4s(sv[t], inv);
      __builtin_amdgcn_s_setprio(1);
      #pragma unroll
      for (int nc = 0; nc < 2; ++nc)
        #pragma unroll
        for (int t = 0; t < 4; ++t)
          osw[2 * h + nc] = mfma16(vn[t][2 * h + nc], pb[t], osw[2 * h + nc]);
      __builtin_amdgcn_s_setprio(0);
    }

    bf4 ofr[6];
    #pragma unroll
    for (int c = 0; c < 6; ++c) ofr[c] = pk4(osw[c]);

    const int gx2 = (p * 4 + qc + 2) & 63, gy2 = (q * 4 + sy + 2) & 63, gz2 = (r * 4 + sz + 2) & 63;
    const size_t b2 = (size_t)((gx2 * 64 + gy2) * 64 + gz2) * 96;
    #pragma unroll
    for (int no = 0; no < 6; ++no) {
      f32x4 acc = {0.f, 0.f, 0.f, 0.f};
      const short* wr = &ls_wo[(no * 16 + lr) * SW + kg * 4];
      #pragma unroll
      for (int c = 0; c < 6; ++c) {
        bf4 wa = *reinterpret_cast<const bf4*>(wr + c * 16);
        acc = mfma16(wa, ofr[c], acc);
      }
      const float4 bb = *reinterpret_cast<const float4*>(&bo[no * 16 + kg * 4]);
      float4 o4;
      o4.x = acc[0] + bb.x; o4.y = acc[1] + bb.y;
      o4.z = acc[2] + bb.z; o4.w = acc[3] + bb.w;
      *reinterpret_cast<float4*>(&out[b2 + no * 16 + kg * 4]) = o4;
    }
  }
}

__global__ __launch_bounds__(256)
__attribute__((amdgpu_waves_per_eu(1, 2)))
void fused_swin3d(const float* __restrict__ x,
                  const short* __restrict__ wpk,   // padded pack in d_ws
                  const float* __restrict__ bo,    // [96] fp32
                  float* __restrict__ out) {
  __shared__ __align__(16) short ls_w[W_SHORTS];   // 76800 B: W_qkv + W_out

  const int tid = threadIdx.x;
  const int wbase = ((int)blockIdx.x * 4 + (tid >> 6)) * 2;  // 2 windows/wave
  const int lane = tid & 63;
  const int lr   = lane & 15;
  const int kg   = lane >> 4;
  const int sy = (lr >> 2) & 3, sz = lr & 3;
  const int ch0 = kg * 8;
  const short* ls_wo = ls_w + WQ_ROWS * SW;

  const int wA = wbase, wB = wbase + 1;
  const int pA = wA >> 8, qA = (wA >> 4) & 15, rA = wA & 15;
  const int pB = wB >> 8, qB = (wB >> 4) & 15, rB = wB & 15;

  // ---- PREFETCH (1): A's xa issued before the weight stage ------------------
  float4 faA[4][6];
  #pragma unroll
  for (int sc = 0; sc < 4; ++sc)
    issue_xa_sc(x, qA, rA, pA, sc, sy, sz, ch0, faA[sc]);   // QK source (q,r,p)

  // ---- stage full weight pack (once per 2 windows) --------------------------
  const float4* wsrc = reinterpret_cast<const float4*>(wpk);
  #pragma unroll
  for (int i = 0; i < 19; ++i) {
    int c = i * 256 + tid;                  // 4800 16B chunks
    if (c < W_SHORTS / 8)
      *reinterpret_cast<float4*>(&ls_w[c * 8]) = wsrc[c];
  }

  // convert A.xa while waiting (frees the float4s before the barrier)
  bf8 x1A[4][3];
  #pragma unroll
  for (int sc = 0; sc < 4; ++sc) cvt_sc(faA[sc], x1A[sc]);

  __syncthreads();                          // the ONLY barrier

  // ================= window A =================
  bf4 qnA[4][6], knA[4][6], vnA[4][6];
  do_p1(ls_w, x1A, lr, ch0, qnA, knA);
  do_p2(x, ls_w, pA, qA, rA, sy, sz, ch0, lr, vnA);

  // ---- PREFETCH (2): B's xa, 2-sc pipelined (hides under A's P3+P4) ---------
  bf8 x1B[4][3];
  {
    float4 f0[6], f1[6];
    issue_xa_sc(x, qB, rB, pB, 0, sy, sz, ch0, f0);
    issue_xa_sc(x, qB, rB, pB, 1, sy, sz, ch0, f1);
    cvt_sc(f0, x1B[0]);
    cvt_sc(f1, x1B[1]);
  }
  {
    float4 f2[6], f3[6];
    issue_xa_sc(x, qB, rB, pB, 2, sy, sz, ch0, f2);
    issue_xa_sc(x, qB, rB, pB, 3, sy, sz, ch0, f3);
    cvt_sc(f2, x1B[2]);
    cvt_sc(f3, x1B[3]);
  }

  do_p34(ls_wo, bo, out, pA, qA, rA, sy, sz, ch0, lr, kg, qnA, knA, vnA);

  // ================= window B =================
  bf4 qnB[4][6], knB[4][6], vnB[4][6];
  do_p1(ls_w, x1B, lr, ch0, qnB, knB);
  do_p2(x, ls_w, pB, qB, rB, sy, sz, ch0, lr, vnB);
  do_p34(ls_wo, bo, out, pB, qB, rB, sy, sz, ch0, lr, kg, qnB, knB, vnB);
}

extern "C" void kernel_launch(void* const* d_in, const int* in_sizes, int n_in,
                              void* d_out, int out_size, void* d_ws, size_t ws_size,
                              hipStream_t stream) {
  const float* x  = (const float*)d_in[0];
  const float* wq = (const float*)d_in[1];
  const float* wo = (const float*)d_in[2];
  const float* bo = (const float*)d_in[3];
  // d_in[4..6] = x_mask/y_mask/z_mask: applied analytically in-kernel.

  short* wpk = (short*)d_ws;               // padded weight pack, 76800 B

  prep_weights<<<(W_SHORTS + 255) / 256, 256, 0, stream>>>(wq, wo, wpk);
  fused_swin3d<<<512, 256, 0, stream>>>(x, wpk, bo, (float*)d_out);
}